// Round 7
// baseline (857.727 us; speedup 1.0000x reference)
//
#include <hip/hip_runtime.h>

// ArDCA loss: loss = -sum_{m,i} W[m] * log_softmax(h[i,:] + sum_{j<i} J[i,j,:,X[m,j]])[X[m,i]]
//             + 1e-6 * sum h^2 + 1e-4 * sum_{j<i} J^2
// M=8192, L=256, Q=21. Output: single fp32 scalar.
//
// R11: two changes on top of R10 (487us total = 330 pair + ~150 transcode):
// 1) Transcode rewrite: direct, barrier-free. One block per pair; each of
//    256 threads produces exactly ONE u32 of the 1024-B output block
//    (b = tid/12, g = tid%12; g>=8 and b>=21 are zero pad). 91 MB streamed
//    -> ~30-40us (was ~150us: 16 serial pairs/block x 3 barriers each).
// 2) Hybrid row payload, gather 3 reads -> 2: row = 11 f16 (a0..a10, 22 B)
//    + 10 fp8-e4m3 x256 (a11..a20, 10 B) in the first 32 B; bytes 32..47
//    dead pad. Stride stays 48 B -> addressing, staging, and conflict math
//    IDENTICAL to R10 ((3b+p) mod 8, max 3-way, now p in {0,1}). LDS-unit
//    cost/wave-j: ~50 -> ~31 cyc (the bound: 1 LDS unit/CU vs 4 SIMDs).
//    Decode: 5x cvt_pk_f32_fp8 + 5x pk_add_f32 (f32 acc); f16 values keep
//    R10's pk_add_f16 path. All-fp8 passed absmax 0 in R7/R9 -> safe.
// Model: LDS 204us floor, VALU ~245us (if cvt is quarter-rate) -> pair
// ~245-270us, total ~300-320us.
// VGPR watch: ~50 expected, must stay <=64. ws: 32640*1024 = 33.4 MB.

#define M_SEQ 8192
#define L_POS 256
#define Q_SYM 21
#define QQ    441
#define JC    12
#define NPAIR 32640                  // 256*255/2
#define PAIRB 1024                   // padded bytes per (i,j) pair in J8
#define CHUNKB (JC * PAIRB)          // 12288 B staged per chunk

typedef _Float16 h2 __attribute__((ext_vector_type(2)));
typedef float f32x2 __attribute__((ext_vector_type(2)));

__device__ __forceinline__ h2 as_h2(unsigned int u) {
    union { unsigned int u; h2 h; } c; c.u = u; return c.h;
}

__device__ __forceinline__ float wave_block_reduce(float v, float* red, int tid) {
    #pragma unroll
    for (int off = 32; off > 0; off >>= 1) v += __shfl_down(v, off, 64);
    if ((tid & 63) == 0) red[tid >> 6] = v;
    __syncthreads();
    return red[0] + red[1] + red[2] + red[3];
}

__device__ __forceinline__ void gload16(const void* g, void* l) {
    __builtin_amdgcn_global_load_lds(
        (const __attribute__((address_space(1))) unsigned int*)g,
        (__attribute__((address_space(3))) unsigned int*)l, 16, 0, 0);
}

__global__ void zero_out(float* __restrict__ out) { out[0] = 0.0f; }

// ---- Kernel A: J[i][j][a][b] (fp32, lower tri) -> J8[pair][b][...] hybrid
//      rows: 11 f16 (a0..a10) + 10 fp8(x256) (a11..a20) in 32 B, 48-B stride,
//      pair block padded to 1024 B. Each thread writes exactly one u32.
//      Also folds 1e-4*sumJ^2 (+1e-6*sumh^2 on block 0).
__global__ __launch_bounds__(256) void transcode_kernel(const float* __restrict__ J,
                                                        const float* __restrict__ h,
                                                        unsigned char* __restrict__ J8,
                                                        float* __restrict__ out) {
    __shared__ float red[4];
    const int tid = threadIdx.x;
    const int p = blockIdx.x;                  // pair index
    // decode p -> (ii, jj)
    int ii = (int)((1.0f + sqrtf((float)(8 * p + 1))) * 0.5f);
    while (ii * (ii - 1) / 2 > p) --ii;
    while ((ii + 1) * ii / 2 <= p) ++ii;
    const int jj = p - ii * (ii - 1) / 2;

    const float* src = J + ((size_t)ii * L_POS + jj) * QQ;
    const int b = tid / 12;                    // row (symbol b)
    const int g = tid - b * 12;                // u32 slot within row (12 = 48 B)
    const float S = 256.0f;
    unsigned int w = 0u;
    float rs = 0.0f;

    if (b < Q_SYM) {
        if (g < 5) {                           // f16 pair (a[2g], a[2g+1])
            float v0 = src[(2 * g)     * Q_SYM + b];
            float v1 = src[(2 * g + 1) * Q_SYM + b];
            rs = v0 * v0 + v1 * v1;
            union { _Float16 h[2]; unsigned int u; } cv;
            cv.h[0] = (_Float16)v0; cv.h[1] = (_Float16)v1;
            w = cv.u;
        } else if (g == 5) {                   // a10 f16 | fp8(a11) | fp8(a12)
            float v0 = src[10 * Q_SYM + b];
            float v1 = src[11 * Q_SYM + b];
            float v2 = src[12 * Q_SYM + b];
            rs = v0 * v0 + v1 * v1 + v2 * v2;
            unsigned int e1 = (unsigned int)__builtin_amdgcn_cvt_pk_fp8_f32(v1 * S, 0.f, 0, false) & 0xffu;
            unsigned int e2 = (unsigned int)__builtin_amdgcn_cvt_pk_fp8_f32(v2 * S, 0.f, 0, false) & 0xffu;
            union { _Float16 h[2]; unsigned int u; } cv;
            cv.h[0] = (_Float16)v0; cv.h[1] = (_Float16)0.f;
            w = (cv.u & 0xffffu) | (e1 << 16) | (e2 << 24);
        } else if (g == 6) {                   // fp8 a13..a16
            float v0 = src[13 * Q_SYM + b], v1 = src[14 * Q_SYM + b];
            float v2 = src[15 * Q_SYM + b], v3 = src[16 * Q_SYM + b];
            rs = v0 * v0 + v1 * v1 + v2 * v2 + v3 * v3;
            int t = __builtin_amdgcn_cvt_pk_fp8_f32(v0 * S, v1 * S, 0, false);
            t     = __builtin_amdgcn_cvt_pk_fp8_f32(v2 * S, v3 * S, t, true);
            w = (unsigned int)t;
        } else if (g == 7) {                   // fp8 a17..a20
            float v0 = src[17 * Q_SYM + b], v1 = src[18 * Q_SYM + b];
            float v2 = src[19 * Q_SYM + b], v3 = src[20 * Q_SYM + b];
            rs = v0 * v0 + v1 * v1 + v2 * v2 + v3 * v3;
            int t = __builtin_amdgcn_cvt_pk_fp8_f32(v0 * S, v1 * S, 0, false);
            t     = __builtin_amdgcn_cvt_pk_fp8_f32(v2 * S, v3 * S, t, true);
            w = (unsigned int)t;
        }                                      // g 8..11: dead pad (zero)
    }
    ((unsigned int*)(J8 + (size_t)p * PAIRB))[tid] = w;   // coalesced 1024-B store

    float acc = 1e-4f * rs;
    if (p == 0) {                              // fold h^2 once
        float hs = 0.0f;
        for (int t = tid; t < L_POS * Q_SYM; t += 256) { float v = h[t]; hs += v * v; }
        acc += 1e-6f * hs;
    }
    float tot = wave_block_reduce(acc, red, tid);
    if (tid == 0) atomicAdd(out, tot);
}

// ---- Kernel B: one block per (m-chunk of 256, i). Each thread owns one m.
__global__ __launch_bounds__(256) void pair_nll_kernel(const int* __restrict__ X,
                                                       const float* __restrict__ W,
                                                       const float* __restrict__ h,
                                                       const unsigned char* __restrict__ J8,
                                                       float* __restrict__ out) {
    __shared__ unsigned char JL[2][CHUNKB];    // 2 x 12288 B
    __shared__ float red[4];

    const int tid = threadIdx.x;
    const int i  = blockIdx.y;
    const int m  = blockIdx.x * 256 + tid;
    const int* xrow = X + (size_t)m * L_POS;
    const unsigned char* jbase = J8 + ((size_t)i * (i - 1) / 2) * PAIRB;

    h2 accF[5];                                // a0..a9 (f16 pairs)
    #pragma unroll
    for (int k = 0; k < 5; ++k) { accF[k].x = (_Float16)0.f; accF[k].y = (_Float16)0.f; }
    _Float16 acc10 = (_Float16)0.f;            // a10
    f32x2 accB[5];                             // (a11,a12)..(a19,a20), f32
    #pragma unroll
    for (int k = 0; k < 5; ++k) { accB[k].x = 0.f; accB[k].y = 0.f; }

    const int nch = (i + JC - 1) / JC;
    const int wbase = (tid >> 6) << 10;        // wave-uniform LDS base offset

    if (nch > 0) {                             // issue chunk 0 (3 issues/thread)
        const unsigned char* g = jbase + tid * 16;
        gload16(g,        &JL[0][wbase]);
        gload16(g + 4096, &JL[0][4096 + wbase]);
        gload16(g + 8192, &JL[0][8192 + wbase]);
    }
    __syncthreads();                           // implicit vmcnt(0): chunk 0 arrived

    for (int k = 0; k < nch; ++k) {
        const int j0 = k * JC;

        // ---- issue chunk k+1 into the other buffer (in flight over gather)
        if (k + 1 < nch) {
            const unsigned char* g = jbase + (size_t)(k + 1) * CHUNKB + tid * 16;
            unsigned char* l = &JL[(k + 1) & 1][wbase];
            gload16(g,        l);
            gload16(g + 4096, l + 4096);
            gload16(g + 8192, l + 8192);
        }

        // ---- this thread's 12 X values (block-uniform guards keep loads in-bounds)
        int4 xA = *(const int4*)(xrow + j0);
        int4 xB = make_int4(0,0,0,0), xC = make_int4(0,0,0,0);
        if (j0 + 4 < i) xB = *(const int4*)(xrow + j0 + 4);
        if (j0 + 8 < i) xC = *(const int4*)(xrow + j0 + 8);
        int xv[JC] = {xA.x, xA.y, xA.z, xA.w, xB.x, xB.y, xB.z, xB.w,
                      xC.x, xC.y, xC.z, xC.w};

        const unsigned char* buf = JL[k & 1];
        #pragma unroll
        for (int jc = 0; jc < JC; ++jc) {
            if (j0 + jc < i) {                 // block-uniform guard
                int b = xv[jc];
                const uint4* r = (const uint4*)(buf + (jc << 10) + b * 48);
                uint4 f0 = r[0];               // a0..a7 f16
                uint4 f1 = r[1];               // a8,a9 f16 | a10 f16 + fp8 a11,a12 | fp8 a13..a16 | fp8 a17..a20
                accF[0] += as_h2(f0.x); accF[1] += as_h2(f0.y);
                accF[2] += as_h2(f0.z); accF[3] += as_h2(f0.w);
                accF[4] += as_h2(f1.x);
                acc10   += as_h2(f1.y).x;
                accB[0] += __builtin_amdgcn_cvt_pk_f32_fp8((int)f1.y, true);
                accB[1] += __builtin_amdgcn_cvt_pk_f32_fp8((int)f1.z, false);
                accB[2] += __builtin_amdgcn_cvt_pk_f32_fp8((int)f1.z, true);
                accB[3] += __builtin_amdgcn_cvt_pk_f32_fp8((int)f1.w, false);
                accB[4] += __builtin_amdgcn_cvt_pk_f32_fp8((int)f1.w, true);
            }
        }

        // one barrier per chunk: drains vmcnt(0) (chunk k+1 arrived) and joins
        // all waves' reads of buf[k&1] before iter k+2 overwrites it.
        __syncthreads();
    }

    // ---- logits = h[i,:] + pair ; log-softmax ; pick gold = X[m,i]
    const float* hrow = h + i * Q_SYM;
    const float INV = 0.00390625f;             // 1/256: undo fp8 encode pre-scale
    float logits[Q_SYM];
    #pragma unroll
    for (int k = 0; k < 5; ++k) {
        logits[2 * k]     = hrow[2 * k]     + (float)accF[k].x;
        logits[2 * k + 1] = hrow[2 * k + 1] + (float)accF[k].y;
    }
    logits[10] = hrow[10] + (float)acc10;
    #pragma unroll
    for (int t = 0; t < 5; ++t) {
        logits[11 + 2 * t] = hrow[11 + 2 * t] + accB[t].x * INV;
        logits[12 + 2 * t] = hrow[12 + 2 * t] + accB[t].y * INV;
    }

    float mx = -3.4e38f;
    #pragma unroll
    for (int a = 0; a < Q_SYM; ++a) mx = fmaxf(mx, logits[a]);
    float s = 0.0f;
    #pragma unroll
    for (int a = 0; a < Q_SYM; ++a) s += __expf(logits[a] - mx);
    int g = xrow[i];
    float gold = 0.0f;
    #pragma unroll
    for (int a = 0; a < Q_SYM; ++a) gold = (a == g) ? logits[a] : gold;
    float logp = gold - mx - __logf(s);
    float v = -W[m] * logp;

    float tot = wave_block_reduce(v, red, tid);
    if (tid == 0) atomicAdd(out, tot);
}

extern "C" void kernel_launch(void* const* d_in, const int* in_sizes, int n_in,
                              void* d_out, int out_size, void* d_ws, size_t ws_size,
                              hipStream_t stream) {
    const int*   X = (const int*)d_in[0];
    const float* W = (const float*)d_in[1];
    const float* h = (const float*)d_in[2];
    const float* J = (const float*)d_in[3];
    float* out = (float*)d_out;
    unsigned char* J8 = (unsigned char*)d_ws;  // needs 32640*1024 = 33.4 MB

    hipLaunchKernelGGL(zero_out, dim3(1), dim3(1), 0, stream, out);
    hipLaunchKernelGGL(transcode_kernel, dim3(NPAIR), dim3(256), 0, stream,
                       J, h, J8, out);
    dim3 grid(M_SEQ / 256, L_POS);
    hipLaunchKernelGGL(pair_nll_kernel, grid, dim3(256), 0, stream, X, W, h, J8, out);
}

// Round 8
// 505.615 us; speedup vs baseline: 1.6964x; 1.6964x over previous
//
#include <hip/hip_runtime.h>

// ArDCA loss: loss = -sum_{m,i} W[m] * log_softmax(h[i,:] + sum_{j<i} J[i,j,:,X[m,j]])[X[m,i]]
//             + 1e-6 * sum h^2 + 1e-4 * sum_{j<i} J^2
// M=8192, L=256, Q=21. Output: single fp32 scalar.
//
// R12: transcode de-serialized. R11 post-mortem: one-pair-per-block made
// 32640 blocks each ending in atomicAdd to the SAME dword -> contended
// same-address RMWs serialize at one L2 slice (~12 ns each ~ 390 us ~ the
// whole 420 us dispatch; VALUBusy 6%, HBM 2%, conflicts 0 = "waiting on a
// serializer"). Fix: keep the direct one-u32-per-thread encode (no LDS
// staging, no per-pair barriers, coalesced 1024-B stores) but batch 16
// pairs per block (thread keeps its slot, loops pairs -> independent loads,
// good MLP); ONE reduce + ONE atomicAdd per block -> 2040 atomics (proven
// hidden in R9/R10).
// Pair kernel: unchanged from R11 (hybrid 11xf16 + 10xfp8 rows, 2 ds_read
// per j) so its cost finally becomes readable in the counters. If it reads
// >330 us, the hybrid format regressed vs R10 and gets reverted next.
// ws: 32640*1024 = 33.4 MB.

#define M_SEQ 8192
#define L_POS 256
#define Q_SYM 21
#define QQ    441
#define JC    12
#define NPAIR 32640                  // 256*255/2
#define PAIRB 1024                   // padded bytes per (i,j) pair in J8
#define CHUNKB (JC * PAIRB)          // 12288 B staged per chunk
#define PPB   16                     // pairs per transcode block

typedef _Float16 h2 __attribute__((ext_vector_type(2)));
typedef float f32x2 __attribute__((ext_vector_type(2)));

__device__ __forceinline__ h2 as_h2(unsigned int u) {
    union { unsigned int u; h2 h; } c; c.u = u; return c.h;
}

__device__ __forceinline__ float wave_block_reduce(float v, float* red, int tid) {
    #pragma unroll
    for (int off = 32; off > 0; off >>= 1) v += __shfl_down(v, off, 64);
    if ((tid & 63) == 0) red[tid >> 6] = v;
    __syncthreads();
    return red[0] + red[1] + red[2] + red[3];
}

__device__ __forceinline__ void gload16(const void* g, void* l) {
    __builtin_amdgcn_global_load_lds(
        (const __attribute__((address_space(1))) unsigned int*)g,
        (__attribute__((address_space(3))) unsigned int*)l, 16, 0, 0);
}

__global__ void zero_out(float* __restrict__ out) { out[0] = 0.0f; }

// ---- Kernel A: J[i][j][a][b] (fp32, lower tri) -> J8[pair][b][...] hybrid
//      rows: 11 f16 (a0..a10) + 10 fp8(x256) (a11..a20) in 32 B, 48-B
//      stride, pair block padded to 1024 B. Thread owns one u32 slot
//      (b = tid/12, g = tid%12) and loops over 16 pairs. One atomic/block.
__global__ __launch_bounds__(256) void transcode_kernel(const float* __restrict__ J,
                                                        const float* __restrict__ h,
                                                        unsigned char* __restrict__ J8,
                                                        float* __restrict__ out) {
    __shared__ float red[4];
    const int tid = threadIdx.x;
    const int p0 = blockIdx.x * PPB;
    // decode pair p0 -> (ii, jj), then walk forward
    int ii = (int)((1.0f + sqrtf((float)(8 * p0 + 1))) * 0.5f);
    while (ii * (ii - 1) / 2 > p0) --ii;
    while ((ii + 1) * ii / 2 <= p0) ++ii;
    int jj = p0 - ii * (ii - 1) / 2;

    const int b = tid / 12;                    // row (symbol b)
    const int g = tid - b * 12;                // u32 slot within row
    const float S = 256.0f;
    float rs = 0.0f;

    for (int p = p0; p < p0 + PPB; ++p) {
        const float* src = J + ((size_t)ii * L_POS + jj) * QQ;
        unsigned int w = 0u;
        if (b < Q_SYM) {
            if (g < 5) {                       // f16 pair (a[2g], a[2g+1])
                float v0 = src[(2 * g)     * Q_SYM + b];
                float v1 = src[(2 * g + 1) * Q_SYM + b];
                rs += v0 * v0 + v1 * v1;
                union { _Float16 h[2]; unsigned int u; } cv;
                cv.h[0] = (_Float16)v0; cv.h[1] = (_Float16)v1;
                w = cv.u;
            } else if (g == 5) {               // a10 f16 | fp8(a11) | fp8(a12)
                float v0 = src[10 * Q_SYM + b];
                float v1 = src[11 * Q_SYM + b];
                float v2 = src[12 * Q_SYM + b];
                rs += v0 * v0 + v1 * v1 + v2 * v2;
                unsigned int e1 = (unsigned int)__builtin_amdgcn_cvt_pk_fp8_f32(v1 * S, 0.f, 0, false) & 0xffu;
                unsigned int e2 = (unsigned int)__builtin_amdgcn_cvt_pk_fp8_f32(v2 * S, 0.f, 0, false) & 0xffu;
                union { _Float16 h[2]; unsigned int u; } cv;
                cv.h[0] = (_Float16)v0; cv.h[1] = (_Float16)0.f;
                w = (cv.u & 0xffffu) | (e1 << 16) | (e2 << 24);
            } else if (g == 6) {               // fp8 a13..a16
                float v0 = src[13 * Q_SYM + b], v1 = src[14 * Q_SYM + b];
                float v2 = src[15 * Q_SYM + b], v3 = src[16 * Q_SYM + b];
                rs += v0 * v0 + v1 * v1 + v2 * v2 + v3 * v3;
                int t = __builtin_amdgcn_cvt_pk_fp8_f32(v0 * S, v1 * S, 0, false);
                t     = __builtin_amdgcn_cvt_pk_fp8_f32(v2 * S, v3 * S, t, true);
                w = (unsigned int)t;
            } else if (g == 7) {               // fp8 a17..a20
                float v0 = src[17 * Q_SYM + b], v1 = src[18 * Q_SYM + b];
                float v2 = src[19 * Q_SYM + b], v3 = src[20 * Q_SYM + b];
                rs += v0 * v0 + v1 * v1 + v2 * v2 + v3 * v3;
                int t = __builtin_amdgcn_cvt_pk_fp8_f32(v0 * S, v1 * S, 0, false);
                t     = __builtin_amdgcn_cvt_pk_fp8_f32(v2 * S, v3 * S, t, true);
                w = (unsigned int)t;
            }                                  // g 8..11: dead pad (zero)
        }
        ((unsigned int*)(J8 + (size_t)p * PAIRB))[tid] = w;   // coalesced
        ++jj; if (jj == ii) { jj = 0; ++ii; }
    }

    float acc = 1e-4f * rs;
    if (blockIdx.x == 0) {                     // fold h^2 once
        float hs = 0.0f;
        for (int t = tid; t < L_POS * Q_SYM; t += 256) { float v = h[t]; hs += v * v; }
        acc += 1e-6f * hs;
    }
    float tot = wave_block_reduce(acc, red, tid);
    if (tid == 0) atomicAdd(out, tot);
}

// ---- Kernel B: one block per (m-chunk of 256, i). Each thread owns one m.
__global__ __launch_bounds__(256) void pair_nll_kernel(const int* __restrict__ X,
                                                       const float* __restrict__ W,
                                                       const float* __restrict__ h,
                                                       const unsigned char* __restrict__ J8,
                                                       float* __restrict__ out) {
    __shared__ unsigned char JL[2][CHUNKB];    // 2 x 12288 B
    __shared__ float red[4];

    const int tid = threadIdx.x;
    const int i  = blockIdx.y;
    const int m  = blockIdx.x * 256 + tid;
    const int* xrow = X + (size_t)m * L_POS;
    const unsigned char* jbase = J8 + ((size_t)i * (i - 1) / 2) * PAIRB;

    h2 accF[5];                                // a0..a9 (f16 pairs)
    #pragma unroll
    for (int k = 0; k < 5; ++k) { accF[k].x = (_Float16)0.f; accF[k].y = (_Float16)0.f; }
    _Float16 acc10 = (_Float16)0.f;            // a10
    f32x2 accB[5];                             // (a11,a12)..(a19,a20), f32
    #pragma unroll
    for (int k = 0; k < 5; ++k) { accB[k].x = 0.f; accB[k].y = 0.f; }

    const int nch = (i + JC - 1) / JC;
    const int wbase = (tid >> 6) << 10;        // wave-uniform LDS base offset

    if (nch > 0) {                             // issue chunk 0 (3 issues/thread)
        const unsigned char* g = jbase + tid * 16;
        gload16(g,        &JL[0][wbase]);
        gload16(g + 4096, &JL[0][4096 + wbase]);
        gload16(g + 8192, &JL[0][8192 + wbase]);
    }
    __syncthreads();                           // implicit vmcnt(0): chunk 0 arrived

    for (int k = 0; k < nch; ++k) {
        const int j0 = k * JC;

        // ---- issue chunk k+1 into the other buffer (in flight over gather)
        if (k + 1 < nch) {
            const unsigned char* g = jbase + (size_t)(k + 1) * CHUNKB + tid * 16;
            unsigned char* l = &JL[(k + 1) & 1][wbase];
            gload16(g,        l);
            gload16(g + 4096, l + 4096);
            gload16(g + 8192, l + 8192);
        }

        // ---- this thread's 12 X values (block-uniform guards keep loads in-bounds)
        int4 xA = *(const int4*)(xrow + j0);
        int4 xB = make_int4(0,0,0,0), xC = make_int4(0,0,0,0);
        if (j0 + 4 < i) xB = *(const int4*)(xrow + j0 + 4);
        if (j0 + 8 < i) xC = *(const int4*)(xrow + j0 + 8);
        int xv[JC] = {xA.x, xA.y, xA.z, xA.w, xB.x, xB.y, xB.z, xB.w,
                      xC.x, xC.y, xC.z, xC.w};

        const unsigned char* buf = JL[k & 1];
        #pragma unroll
        for (int jc = 0; jc < JC; ++jc) {
            if (j0 + jc < i) {                 // block-uniform guard
                int b = xv[jc];
                const uint4* r = (const uint4*)(buf + (jc << 10) + b * 48);
                uint4 f0 = r[0];               // a0..a7 f16
                uint4 f1 = r[1];               // a8,a9 | a10 + fp8 a11,a12 | fp8 a13..a16 | fp8 a17..a20
                accF[0] += as_h2(f0.x); accF[1] += as_h2(f0.y);
                accF[2] += as_h2(f0.z); accF[3] += as_h2(f0.w);
                accF[4] += as_h2(f1.x);
                acc10   += as_h2(f1.y).x;
                accB[0] += __builtin_amdgcn_cvt_pk_f32_fp8((int)f1.y, true);
                accB[1] += __builtin_amdgcn_cvt_pk_f32_fp8((int)f1.z, false);
                accB[2] += __builtin_amdgcn_cvt_pk_f32_fp8((int)f1.z, true);
                accB[3] += __builtin_amdgcn_cvt_pk_f32_fp8((int)f1.w, false);
                accB[4] += __builtin_amdgcn_cvt_pk_f32_fp8((int)f1.w, true);
            }
        }

        // one barrier per chunk: drains vmcnt(0) (chunk k+1 arrived) and joins
        // all waves' reads of buf[k&1] before iter k+2 overwrites it.
        __syncthreads();
    }

    // ---- logits = h[i,:] + pair ; log-softmax ; pick gold = X[m,i]
    const float* hrow = h + i * Q_SYM;
    const float INV = 0.00390625f;             // 1/256: undo fp8 encode pre-scale
    float logits[Q_SYM];
    #pragma unroll
    for (int k = 0; k < 5; ++k) {
        logits[2 * k]     = hrow[2 * k]     + (float)accF[k].x;
        logits[2 * k + 1] = hrow[2 * k + 1] + (float)accF[k].y;
    }
    logits[10] = hrow[10] + (float)acc10;
    #pragma unroll
    for (int t = 0; t < 5; ++t) {
        logits[11 + 2 * t] = hrow[11 + 2 * t] + accB[t].x * INV;
        logits[12 + 2 * t] = hrow[12 + 2 * t] + accB[t].y * INV;
    }

    float mx = -3.4e38f;
    #pragma unroll
    for (int a = 0; a < Q_SYM; ++a) mx = fmaxf(mx, logits[a]);
    float s = 0.0f;
    #pragma unroll
    for (int a = 0; a < Q_SYM; ++a) s += __expf(logits[a] - mx);
    int g = xrow[i];
    float gold = 0.0f;
    #pragma unroll
    for (int a = 0; a < Q_SYM; ++a) gold = (a == g) ? logits[a] : gold;
    float logp = gold - mx - __logf(s);
    float v = -W[m] * logp;

    float tot = wave_block_reduce(v, red, tid);
    if (tid == 0) atomicAdd(out, tot);
}

extern "C" void kernel_launch(void* const* d_in, const int* in_sizes, int n_in,
                              void* d_out, int out_size, void* d_ws, size_t ws_size,
                              hipStream_t stream) {
    const int*   X = (const int*)d_in[0];
    const float* W = (const float*)d_in[1];
    const float* h = (const float*)d_in[2];
    const float* J = (const float*)d_in[3];
    float* out = (float*)d_out;
    unsigned char* J8 = (unsigned char*)d_ws;  // needs 32640*1024 = 33.4 MB

    hipLaunchKernelGGL(zero_out, dim3(1), dim3(1), 0, stream, out);
    hipLaunchKernelGGL(transcode_kernel, dim3(NPAIR / PPB), dim3(256), 0, stream,
                       J, h, J8, out);
    dim3 grid(M_SEQ / 256, L_POS);
    hipLaunchKernelGGL(pair_nll_kernel, grid, dim3(256), 0, stream, X, W, h, J8, out);
}

// Round 9
// 483.963 us; speedup vs baseline: 1.7723x; 1.0447x over previous
//
#include <hip/hip_runtime.h>

// ArDCA loss: loss = -sum_{m,i} W[m] * log_softmax(h[i,:] + sum_{j<i} J[i,j,:,X[m,j]])[X[m,i]]
//             + 1e-6 * sum h^2 + 1e-4 * sum_{j<i} J^2
// M=8192, L=256, Q=21. Output: single fp32 scalar.
//
// R13: kill the gather bank conflicts + rewrite transcode.
// R12 post-mortem: pair kernel pinned at 329us, LDS-unit ~94% busy with 42%
// of that CONFLICT stalls (8.04e7 cyc). Root cause: ds_read_b128 lanes
// occupy 16-B bank SPANS; only 8 spans exist -> 21 rows pigeonhole >=3-way
// at any stride. ds_read_b64 has 16 spans: row stride 40 B (10 dw) gives
// span class (5b+q) mod 16, 5 invertible mod 16 -> max 2-way = FREE (m136).
//  - Rows: same hybrid 32-B payload (11 f16 a0..a10 + 10 fp8(x256) a11..a20)
//    at 40-B stride; pair block still 1024 B (21*40=840+pad) -> JC=12,
//    CHUNKB=12288, staging identical. Gather = 4x ds_read_b64.
//  - Transcode: R12's took ~150us, latency-bound on scattered stride-84B
//    scalar reads. New: one pair per WAVE (zero barriers): stage raw 1764 B
//    coalesced into per-wave LDS (7 dw/lane), wave-internal lgkmcnt wait
//    (DS in-order per wave), each lane encodes 4 u32 slots (b=s/10, g=s%10)
//    and stores the 1024-B block coalesced. J^2 folded over staged values.
// ws: 32640*1024 = 33.4 MB.

#define M_SEQ 8192
#define L_POS 256
#define Q_SYM 21
#define QQ    441
#define JC    12
#define NPAIR 32640                  // 256*255/2
#define PAIRB 1024                   // padded bytes per (i,j) pair in J8
#define ROWB  40                     // bytes per row b (32 payload + 8 pad)
#define CHUNKB (JC * PAIRB)          // 12288 B staged per chunk
#define PPW   4                      // pairs per wave (transcode)
#define PPB   16                     // pairs per block = 4 waves * PPW

typedef _Float16 h2 __attribute__((ext_vector_type(2)));
typedef float f32x2 __attribute__((ext_vector_type(2)));

__device__ __forceinline__ h2 as_h2(unsigned int u) {
    union { unsigned int u; h2 h; } c; c.u = u; return c.h;
}

__device__ __forceinline__ float wave_block_reduce(float v, float* red, int tid) {
    #pragma unroll
    for (int off = 32; off > 0; off >>= 1) v += __shfl_down(v, off, 64);
    if ((tid & 63) == 0) red[tid >> 6] = v;
    __syncthreads();
    return red[0] + red[1] + red[2] + red[3];
}

__device__ __forceinline__ void gload16(const void* g, void* l) {
    __builtin_amdgcn_global_load_lds(
        (const __attribute__((address_space(1))) unsigned int*)g,
        (__attribute__((address_space(3))) unsigned int*)l, 16, 0, 0);
}

__global__ void zero_out(float* __restrict__ out) { out[0] = 0.0f; }

// ---- Kernel A: J[i][j][a][b] (fp32, lower tri) -> J8[pair] blocks of
//      1024 B: row b at b*40, payload 11 f16 + 10 fp8(x256). One pair per
//      wave, barrier-free; coalesced load + LDS transpose + coalesced store.
__global__ __launch_bounds__(256) void transcode_kernel(const float* __restrict__ J,
                                                        const float* __restrict__ h,
                                                        unsigned char* __restrict__ J8,
                                                        float* __restrict__ out) {
    __shared__ float raw[4][448];              // per-wave staging (441 used)
    __shared__ float red[4];
    const int tid  = threadIdx.x;
    const int wid  = tid >> 6;
    const int lane = tid & 63;

    int p = blockIdx.x * PPB + wid * PPW;      // first pair for this wave
    // decode p -> (ii, jj)
    int ii = (int)((1.0f + sqrtf((float)(8 * p + 1))) * 0.5f);
    while (ii * (ii - 1) / 2 > p) --ii;
    while ((ii + 1) * ii / 2 <= p) ++ii;
    int jj = p - ii * (ii - 1) / 2;

    const float S = 256.0f;
    float rs = 0.0f;
    float* mybuf = raw[wid];

    for (int t = 0; t < PPW; ++t, ++p) {
        const float* src = J + ((size_t)ii * L_POS + jj) * QQ;
        // ---- coalesced stage: 7 dwords per lane
        #pragma unroll
        for (int r = 0; r < 7; ++r) {
            int idx = lane + 64 * r;
            if (idx < QQ) {
                float v = src[idx];
                rs += v * v;                   // each lower-tri value once
                mybuf[idx] = v;
            }
        }
        asm volatile("s_waitcnt lgkmcnt(0)" ::: "memory");
        __builtin_amdgcn_wave_barrier();

        // ---- each lane encodes 4 u32 slots; coalesced 1024-B store
        unsigned int* dst = (unsigned int*)(J8 + (size_t)p * PAIRB);
        #pragma unroll
        for (int r = 0; r < 4; ++r) {
            int s = lane + 64 * r;
            int b = s / 10, g = s - 10 * b;    // row, u32 slot within row
            unsigned int w = 0u;
            if (b < Q_SYM) {
                const float* col = mybuf + b;  // col[a*21]
                if (g < 5) {                   // f16 pair (a[2g], a[2g+1])
                    union { _Float16 h[2]; unsigned int u; } cv;
                    cv.h[0] = (_Float16)col[(2 * g)     * Q_SYM];
                    cv.h[1] = (_Float16)col[(2 * g + 1) * Q_SYM];
                    w = cv.u;
                } else if (g == 5) {           // a10 f16 | fp8 a11 | fp8 a12
                    union { _Float16 h[2]; unsigned int u; } cv;
                    cv.h[0] = (_Float16)col[10 * Q_SYM]; cv.h[1] = (_Float16)0.f;
                    unsigned int e1 = (unsigned int)__builtin_amdgcn_cvt_pk_fp8_f32(col[11 * Q_SYM] * S, 0.f, 0, false) & 0xffu;
                    unsigned int e2 = (unsigned int)__builtin_amdgcn_cvt_pk_fp8_f32(col[12 * Q_SYM] * S, 0.f, 0, false) & 0xffu;
                    w = (cv.u & 0xffffu) | (e1 << 16) | (e2 << 24);
                } else if (g == 6) {           // fp8 a13..a16
                    int t8 = __builtin_amdgcn_cvt_pk_fp8_f32(col[13 * Q_SYM] * S, col[14 * Q_SYM] * S, 0, false);
                    t8     = __builtin_amdgcn_cvt_pk_fp8_f32(col[15 * Q_SYM] * S, col[16 * Q_SYM] * S, t8, true);
                    w = (unsigned int)t8;
                } else if (g == 7) {           // fp8 a17..a20
                    int t8 = __builtin_amdgcn_cvt_pk_fp8_f32(col[17 * Q_SYM] * S, col[18 * Q_SYM] * S, 0, false);
                    t8     = __builtin_amdgcn_cvt_pk_fp8_f32(col[19 * Q_SYM] * S, col[20 * Q_SYM] * S, t8, true);
                    w = (unsigned int)t8;
                }                              // g 8,9: pad
            }
            dst[s] = w;
        }
        __builtin_amdgcn_wave_barrier();       // raw[] reuse ordering (DS in-order per wave)
        ++jj; if (jj == ii) { jj = 0; ++ii; }
    }

    float acc = 1e-4f * rs;
    if (blockIdx.x == 0) {                     // fold h^2 once
        float hs = 0.0f;
        for (int t = tid; t < L_POS * Q_SYM; t += 256) { float v = h[t]; hs += v * v; }
        acc += 1e-6f * hs;
    }
    float tot = wave_block_reduce(acc, red, tid);
    if (tid == 0) atomicAdd(out, tot);
}

// ---- Kernel B: one block per (m-chunk of 256, i). Each thread owns one m.
__global__ __launch_bounds__(256) void pair_nll_kernel(const int* __restrict__ X,
                                                       const float* __restrict__ W,
                                                       const float* __restrict__ h,
                                                       const unsigned char* __restrict__ J8,
                                                       float* __restrict__ out) {
    __shared__ unsigned char JL[2][CHUNKB];    // 2 x 12288 B
    __shared__ float red[4];

    const int tid = threadIdx.x;
    const int i  = blockIdx.y;
    const int m  = blockIdx.x * 256 + tid;
    const int* xrow = X + (size_t)m * L_POS;
    const unsigned char* jbase = J8 + ((size_t)i * (i - 1) / 2) * PAIRB;

    h2 accF[5];                                // a0..a9 (f16 pairs)
    #pragma unroll
    for (int k = 0; k < 5; ++k) { accF[k].x = (_Float16)0.f; accF[k].y = (_Float16)0.f; }
    _Float16 acc10 = (_Float16)0.f;            // a10
    f32x2 accB[5];                             // (a11,a12)..(a19,a20), f32
    #pragma unroll
    for (int k = 0; k < 5; ++k) { accB[k].x = 0.f; accB[k].y = 0.f; }

    const int nch = (i + JC - 1) / JC;
    const int wbase = (tid >> 6) << 10;        // wave-uniform LDS base offset

    if (nch > 0) {                             // issue chunk 0 (3 issues/thread)
        const unsigned char* g = jbase + tid * 16;
        gload16(g,        &JL[0][wbase]);
        gload16(g + 4096, &JL[0][4096 + wbase]);
        gload16(g + 8192, &JL[0][8192 + wbase]);
    }
    __syncthreads();                           // implicit vmcnt(0): chunk 0 arrived

    for (int k = 0; k < nch; ++k) {
        const int j0 = k * JC;

        // ---- issue chunk k+1 into the other buffer (in flight over gather)
        if (k + 1 < nch) {
            const unsigned char* g = jbase + (size_t)(k + 1) * CHUNKB + tid * 16;
            unsigned char* l = &JL[(k + 1) & 1][wbase];
            gload16(g,        l);
            gload16(g + 4096, l + 4096);
            gload16(g + 8192, l + 8192);
        }

        // ---- this thread's 12 X values (block-uniform guards keep loads in-bounds)
        int4 xA = *(const int4*)(xrow + j0);
        int4 xB = make_int4(0,0,0,0), xC = make_int4(0,0,0,0);
        if (j0 + 4 < i) xB = *(const int4*)(xrow + j0 + 4);
        if (j0 + 8 < i) xC = *(const int4*)(xrow + j0 + 8);
        int xv[JC] = {xA.x, xA.y, xA.z, xA.w, xB.x, xB.y, xB.z, xB.w,
                      xC.x, xC.y, xC.z, xC.w};

        const unsigned char* buf = JL[k & 1];
        #pragma unroll
        for (int jc = 0; jc < JC; ++jc) {
            if (j0 + jc < i) {                 // block-uniform guard
                int b = xv[jc];
                const unsigned char* rb = buf + (jc << 10) + b * ROWB;
                // 4x ds_read_b64: span class (5b+q) mod 16 -> max 2-way (free)
                uint2 q0 = *(const uint2*)(rb);        // a0..a3 f16
                uint2 q1 = *(const uint2*)(rb + 8);    // a4..a7 f16
                uint2 q2 = *(const uint2*)(rb + 16);   // a8,a9 | a10,fp8 a11,a12
                uint2 q3 = *(const uint2*)(rb + 24);   // fp8 a13..a20
                accF[0] += as_h2(q0.x); accF[1] += as_h2(q0.y);
                accF[2] += as_h2(q1.x); accF[3] += as_h2(q1.y);
                accF[4] += as_h2(q2.x);
                acc10   += as_h2(q2.y).x;
                accB[0] += __builtin_amdgcn_cvt_pk_f32_fp8((int)q2.y, true);
                accB[1] += __builtin_amdgcn_cvt_pk_f32_fp8((int)q3.x, false);
                accB[2] += __builtin_amdgcn_cvt_pk_f32_fp8((int)q3.x, true);
                accB[3] += __builtin_amdgcn_cvt_pk_f32_fp8((int)q3.y, false);
                accB[4] += __builtin_amdgcn_cvt_pk_f32_fp8((int)q3.y, true);
            }
        }

        // one barrier per chunk: drains vmcnt(0) (chunk k+1 arrived) and joins
        // all waves' reads of buf[k&1] before iter k+2 overwrites it.
        __syncthreads();
    }

    // ---- logits = h[i,:] + pair ; log-softmax ; pick gold = X[m,i]
    const float* hrow = h + i * Q_SYM;
    const float INV = 0.00390625f;             // 1/256: undo fp8 encode pre-scale
    float logits[Q_SYM];
    #pragma unroll
    for (int k = 0; k < 5; ++k) {
        logits[2 * k]     = hrow[2 * k]     + (float)accF[k].x;
        logits[2 * k + 1] = hrow[2 * k + 1] + (float)accF[k].y;
    }
    logits[10] = hrow[10] + (float)acc10;
    #pragma unroll
    for (int t = 0; t < 5; ++t) {
        logits[11 + 2 * t] = hrow[11 + 2 * t] + accB[t].x * INV;
        logits[12 + 2 * t] = hrow[12 + 2 * t] + accB[t].y * INV;
    }

    float mx = -3.4e38f;
    #pragma unroll
    for (int a = 0; a < Q_SYM; ++a) mx = fmaxf(mx, logits[a]);
    float s = 0.0f;
    #pragma unroll
    for (int a = 0; a < Q_SYM; ++a) s += __expf(logits[a] - mx);
    int g = xrow[i];
    float gold = 0.0f;
    #pragma unroll
    for (int a = 0; a < Q_SYM; ++a) gold = (a == g) ? logits[a] : gold;
    float logp = gold - mx - __logf(s);
    float v = -W[m] * logp;

    float tot = wave_block_reduce(v, red, tid);
    if (tid == 0) atomicAdd(out, tot);
}

extern "C" void kernel_launch(void* const* d_in, const int* in_sizes, int n_in,
                              void* d_out, int out_size, void* d_ws, size_t ws_size,
                              hipStream_t stream) {
    const int*   X = (const int*)d_in[0];
    const float* W = (const float*)d_in[1];
    const float* h = (const float*)d_in[2];
    const float* J = (const float*)d_in[3];
    float* out = (float*)d_out;
    unsigned char* J8 = (unsigned char*)d_ws;  // needs 32640*1024 = 33.4 MB

    hipLaunchKernelGGL(zero_out, dim3(1), dim3(1), 0, stream, out);
    hipLaunchKernelGGL(transcode_kernel, dim3(NPAIR / PPB), dim3(256), 0, stream,
                       J, h, J8, out);
    dim3 grid(M_SEQ / 256, L_POS);
    hipLaunchKernelGGL(pair_nll_kernel, grid, dim3(256), 0, stream, X, W, h, J8, out);
}